// Round 11
// baseline (366.044 us; speedup 1.0000x reference)
//
#include <hip/hip_runtime.h>
#include <hip/hip_bf16.h>

// Problem: B=2048, DIM=2048, SKETCH=256, SIZE=131072
//   sx = normalize_rows(x @ R); out = 1 - max_row(sx @ buffer^T)

#define BROWS 2048
#define DIM   2048
#define SKDIM 256
#define NBUF  131072

// gemm_sim v12: A-in-regs + DIRECT global->reg B streaming. No LDS in the
// main loop, no barriers, no manual vmcnt: each wave double-buffers its own
// 8-frag B window from L2 (B is L2/L3-resident; 32KB/block-window = ~31
// B/cyc/CU vs ~56 budget). Compiler inserts counted vmcnt for the 2-deep
// pipeline. Waves run fully asynchronously.
#define NGROUPS 32            // n-chunks (4096 cols each)
#define NT_PER  32            // 128-col n-tiles per block

typedef __attribute__((ext_vector_type(4))) float f32x4;
typedef __attribute__((ext_vector_type(8))) short bf16x8;
typedef __attribute__((ext_vector_type(4))) short bf16x4;

static __device__ inline unsigned short f2bf(float f) {
  unsigned u = __float_as_uint(f);
  unsigned r = u + 0x7FFFu + ((u >> 16) & 1u);  // round-to-nearest-even
  return (unsigned short)(r >> 16);
}

static __device__ inline bf16x8 cvt8(const float* __restrict__ p) {
  f32x4 a = *(const f32x4*)p;
  f32x4 b = *(const f32x4*)(p + 4);
  bf16x8 r;
  r[0] = (short)f2bf(a[0]); r[1] = (short)f2bf(a[1]);
  r[2] = (short)f2bf(a[2]); r[3] = (short)f2bf(a[3]);
  r[4] = (short)f2bf(b[0]); r[5] = (short)f2bf(b[1]);
  r[6] = (short)f2bf(b[2]); r[7] = (short)f2bf(b[3]);
  return r;
}

// K0: RT_bf[n][k] = bf16(R[k][n])   (256 x 2048)
__global__ void transpose_R(const float* __restrict__ R, unsigned short* __restrict__ rt) {
  int idx = blockIdx.x * 256 + threadIdx.x;
  int k = idx >> 8, n = idx & 255;
  rt[n * DIM + k] = f2bf(R[idx]);
}

// K1+K2 fused: blocks 0..31 = gemm_sketch; blocks 32..2079 = conv_buf.
__launch_bounds__(256)
__global__ void sketch_conv(const float* __restrict__ x, const unsigned short* __restrict__ rt,
                            unsigned short* __restrict__ sx,
                            const float* __restrict__ bufin, unsigned short* __restrict__ outb) {
  __shared__ unsigned short As[64][72];
  __shared__ unsigned short Bs[256][72];
  __shared__ float ssum[4][64];

  if (blockIdx.x >= 32) {
    // ---- conv path ----
    const int nvec = (NBUF * SKDIM) / 4;
    int stride = 2048 * 256;
    for (int i = (blockIdx.x - 32) * 256 + threadIdx.x; i < nvec; i += stride) {
      f32x4 v = ((const f32x4*)bufin)[i];
      bf16x4 r;
      r[0] = (short)f2bf(v[0]); r[1] = (short)f2bf(v[1]);
      r[2] = (short)f2bf(v[2]); r[3] = (short)f2bf(v[3]);
      ((bf16x4*)outb)[i] = r;
    }
    return;
  }

  // ---- sketch path (validated R0-R9) ----
  const int m0 = blockIdx.x * 64;
  const int tid = threadIdx.x;
  const int w = tid >> 6, l = tid & 63;
  const int lr = l & 15, q = l >> 4;

  f32x4 acc[4][4] = {};

  for (int k0 = 0; k0 < DIM; k0 += 64) {
    #pragma unroll
    for (int i = 0; i < 2; ++i) {
      int v = tid + i * 256;
      int r = v >> 3, vc = v & 7;
      *(bf16x8*)&As[r][vc * 8] = cvt8(x + (size_t)(m0 + r) * DIM + k0 + vc * 8);
    }
    #pragma unroll
    for (int i = 0; i < 8; ++i) {
      int v = tid + i * 256;
      int r = v >> 3, vc = v & 7;
      *(bf16x8*)&Bs[r][vc * 8] = *(const bf16x8*)(rt + (size_t)r * DIM + k0 + vc * 8);
    }
    __syncthreads();
    #pragma unroll
    for (int ks = 0; ks < 2; ++ks) {
      int kk = ks * 32 + q * 8;
      bf16x8 a[4], b[4];
      #pragma unroll
      for (int mi = 0; mi < 4; ++mi) a[mi] = *(bf16x8*)&As[mi * 16 + lr][kk];
      #pragma unroll
      for (int ni = 0; ni < 4; ++ni) b[ni] = *(bf16x8*)&Bs[w * 64 + ni * 16 + lr][kk];
      #pragma unroll
      for (int mi = 0; mi < 4; ++mi)
        #pragma unroll
        for (int ni = 0; ni < 4; ++ni)
          acc[mi][ni] = __builtin_amdgcn_mfma_f32_16x16x32_bf16(a[mi], b[ni], acc[mi][ni], 0, 0, 0);
    }
    __syncthreads();
  }

  float ps[4][4];
  #pragma unroll
  for (int mi = 0; mi < 4; ++mi)
    #pragma unroll
    for (int rg = 0; rg < 4; ++rg) {
      float s = acc[mi][0][rg] * acc[mi][0][rg] + acc[mi][1][rg] * acc[mi][1][rg]
              + acc[mi][2][rg] * acc[mi][2][rg] + acc[mi][3][rg] * acc[mi][3][rg];
      #pragma unroll
      for (int m = 1; m < 16; m <<= 1) s += __shfl_xor(s, m);
      ps[mi][rg] = s;
    }
  if (lr == 0) {
    #pragma unroll
    for (int mi = 0; mi < 4; ++mi)
      #pragma unroll
      for (int rg = 0; rg < 4; ++rg)
        ssum[w][mi * 16 + q * 4 + rg] = ps[mi][rg];
  }
  __syncthreads();

  #pragma unroll
  for (int mi = 0; mi < 4; ++mi)
    #pragma unroll
    for (int rg = 0; rg < 4; ++rg) {
      int r = mi * 16 + q * 4 + rg;
      float tot = ssum[0][r] + ssum[1][r] + ssum[2][r] + ssum[3][r];
      float inv = 1.0f / fmaxf(sqrtf(tot), 1e-12f);
      #pragma unroll
      for (int ni = 0; ni < 4; ++ni) {
        float val = acc[mi][ni][rg] * inv;
        sx[(size_t)(m0 + r) * SKDIM + w * 64 + ni * 16 + lr] = f2bf(val);
      }
    }
}

// K3 v12: A-in-regs, direct global->reg B double-buffer, barrier-free.
// Wave (wr,wc) owns rows m0+wr*64..+64, cols wc*64..+64 of each n-tile.
// B frag (16x16x32): lane l holds B[col = base+ni*16+(l&15)][k = (l>>4)*8..+8]
// = bufb[(colrow)*SKDIM + k] -> one 16B load per (ni, chunk).
// Window = 64 k (2 chunks x 4 ni = 8 loads, 32 MFMA). Buffers alternate by
// ks parity (compile-time). Loads for window g+1 issue BEFORE burst g ->
// ~620-cycle shadow; compiler emits counted vmcnt(8) before consumption.
__launch_bounds__(256, 2)
__global__ void gemm_sim(const unsigned short* __restrict__ sx,
                         const unsigned short* __restrict__ bufb,
                         float* __restrict__ partial) {
  __shared__ float rmaxs[256];

  // XCD-chunked swizzle (512 blocks = 8 XCDs x 64), m-fastest inner.
  const int gid = blockIdx.x;
  const int logical = (gid & 7) * 64 + (gid >> 3);
  const int mt = logical & 15;       // 0..15 m-tile (128 rows)
  const int nc = logical >> 4;       // 0..31 n-chunk (4096 cols)
  const int m0 = mt * 128;
  const int ncbase = nc * (NT_PER * 128);

  const int tid = threadIdx.x;
  const int w = tid >> 6, l = tid & 63;
  const int wr = w >> 1, wc = w & 1;        // wave grid 2 x 2
  const int lr = l & 15, q = l >> 4;

  // ---- A resident in registers: rows m0+wr*64+mi*16+lr, k = kc*32+q*8
  bf16x8 areg[4][8];
  {
    const unsigned short* abase = sx + (size_t)(m0 + wr * 64 + lr) * SKDIM + q * 8;
    #pragma unroll
    for (int mi = 0; mi < 4; ++mi)
      #pragma unroll
      for (int kc = 0; kc < 8; ++kc)
        areg[mi][kc] = *(const bf16x8*)(abase + mi * 16 * SKDIM + kc * 32);
  }

  f32x4 acc[4][4] = {};
  float rm[4][4];
  #pragma unroll
  for (int mi = 0; mi < 4; ++mi)
    #pragma unroll
    for (int rg = 0; rg < 4; ++rg) rm[mi][rg] = -3.0e38f;

  bf16x8 bufE[8], bufO[8];   // window double buffer (even-ks / odd-ks)

  // per-lane B base: col-row = ncbase + wc*64 + lr, k-offset q*8
  const unsigned short* bp = bufb + (size_t)(ncbase + wc * 64 + lr) * SKDIM + q * 8;

  // LOADW: 8 frags of window (bp_, ks_): ni-rows +ni*16*SKDIM, chunks +0/+32
#define LOADW(buf, bp_, ks_) do {                                              \
    _Pragma("unroll")                                                          \
    for (int ni = 0; ni < 4; ++ni) {                                           \
      buf[ni]     = *(const bf16x8*)((bp_) + ni * 16 * SKDIM + (ks_) * 64);    \
      buf[4 + ni] = *(const bf16x8*)((bp_) + ni * 16 * SKDIM + (ks_) * 64 + 32); \
    }                                                                          \
  } while (0)

#define BURST(buf, ks) do {                                                    \
    __builtin_amdgcn_s_setprio(1);                                             \
    _Pragma("unroll")                                                          \
    for (int mi = 0; mi < 4; ++mi)                                             \
      _Pragma("unroll")                                                        \
      for (int ni = 0; ni < 4; ++ni)                                           \
        acc[mi][ni] = __builtin_amdgcn_mfma_f32_16x16x32_bf16(areg[mi][(ks) * 2], buf[ni], acc[mi][ni], 0, 0, 0); \
    _Pragma("unroll")                                                          \
    for (int mi = 0; mi < 4; ++mi)                                             \
      _Pragma("unroll")                                                        \
      for (int ni = 0; ni < 4; ++ni)                                           \
        acc[mi][ni] = __builtin_amdgcn_mfma_f32_16x16x32_bf16(areg[mi][(ks) * 2 + 1], buf[4 + ni], acc[mi][ni], 0, 0, 0); \
    __builtin_amdgcn_s_setprio(0);                                             \
  } while (0)

#define FOLD do {                                                              \
    _Pragma("unroll")                                                          \
    for (int mi = 0; mi < 4; ++mi)                                             \
      _Pragma("unroll")                                                        \
      for (int rg = 0; rg < 4; ++rg) {                                         \
        float v = fmaxf(fmaxf(acc[mi][0][rg], acc[mi][1][rg]),                 \
                        fmaxf(acc[mi][2][rg], acc[mi][3][rg]));                \
        rm[mi][rg] = fmaxf(rm[mi][rg], v);                                     \
        _Pragma("unroll")                                                      \
        for (int ni = 0; ni < 4; ++ni) acc[mi][ni][rg] = 0.0f;                 \
      }                                                                        \
  } while (0)

  // prologue: window (nt=0, ks=0) -> bufE
  LOADW(bufE, bp, 0);

  for (int nt = 0; nt < NT_PER; ++nt) {
    // ks=0: load (nt,1)->bufO ; compute bufE
    LOADW(bufO, bp, 1);
    BURST(bufE, 0);
    // ks=1: load (nt,2)->bufE ; compute bufO
    LOADW(bufE, bp, 2);
    BURST(bufO, 1);
    // ks=2: load (nt,3)->bufO ; compute bufE
    LOADW(bufO, bp, 3);
    BURST(bufE, 2);
    // ks=3: load (nt+1,0)->bufE ; compute bufO
    bp += 128 * SKDIM;
    if (nt < NT_PER - 1) LOADW(bufE, bp, 0);
    BURST(bufO, 3);
    FOLD;
  }
#undef LOADW
#undef BURST
#undef FOLD

  // epilogue: reduce over the 16 cols held across lr lanes
  #pragma unroll
  for (int mi = 0; mi < 4; ++mi)
    #pragma unroll
    for (int rg = 0; rg < 4; ++rg) {
      float v = rm[mi][rg];
      v = fmaxf(v, __shfl_xor(v, 1));
      v = fmaxf(v, __shfl_xor(v, 2));
      v = fmaxf(v, __shfl_xor(v, 4));
      v = fmaxf(v, __shfl_xor(v, 8));
      rm[mi][rg] = v;
    }

  if (lr == 0) {
    #pragma unroll
    for (int mi = 0; mi < 4; ++mi)
      #pragma unroll
      for (int rg = 0; rg < 4; ++rg)
        rmaxs[wc * 128 + wr * 64 + mi * 16 + q * 4 + rg] = rm[mi][rg];
  }
  __syncthreads();
  if (tid < 128) {
    float v = fmaxf(rmaxs[tid], rmaxs[128 + tid]);
    partial[(size_t)(m0 + tid) * NGROUPS + nc] = v;
  }
}

// K4: out[r] = 1 - max over 32 partials. 2 rows per 64-thread block.
__global__ void reduce_max(const float* __restrict__ partial, float* __restrict__ out) {
  const int r = blockIdx.x * 2 + (threadIdx.x >> 5);
  const int c = threadIdx.x & 31;
  float m = partial[(size_t)r * NGROUPS + c];
  #pragma unroll
  for (int s = 1; s < 32; s <<= 1) m = fmaxf(m, __shfl_xor(m, s));
  if (c == 0) out[r] = 1.0f - m;
}

extern "C" void kernel_launch(void* const* d_in, const int* in_sizes, int n_in,
                              void* d_out, int out_size, void* d_ws, size_t ws_size,
                              hipStream_t stream) {
  const float* x   = (const float*)d_in[0];   // [2048, 2048]
  const float* R   = (const float*)d_in[1];   // [2048, 256]
  const float* buf = (const float*)d_in[2];   // [131072, 256]
  float* out = (float*)d_out;                  // [2048]

  char* ws = (char*)d_ws;
  // ws layout: rt 1MB | buf_bf 64MB | sx_bf 1MB | partial 256KB
  unsigned short* rt   = (unsigned short*)(ws);
  unsigned short* bufb = (unsigned short*)(ws + (1ull << 20));
  unsigned short* sxb  = (unsigned short*)(ws + (1ull << 20) + (64ull << 20));
  float*          part = (float*)         (ws + (1ull << 20) + (64ull << 20) + (1ull << 20));

  transpose_R<<<dim3((DIM * SKDIM) / 256), dim3(256), 0, stream>>>(R, rt);
  sketch_conv<<<dim3(2080), dim3(256), 0, stream>>>(x, rt, sxb, buf, bufb);
  gemm_sim<<<dim3(512), dim3(256), 0, stream>>>(sxb, bufb, part);
  reduce_max<<<dim3(BROWS / 2), dim3(64), 0, stream>>>(part, out);
}

// Round 12
// 170.384 us; speedup vs baseline: 2.1483x; 2.1483x over previous
//
#include <hip/hip_runtime.h>
#include <hip/hip_bf16.h>

// Problem: B=2048, DIM=2048, SKETCH=256, SIZE=131072
//   sx = normalize_rows(x @ R); out = 1 - max_row(sx @ buffer^T)

#define BROWS 2048
#define DIM   2048
#define SKDIM 256
#define NBUF  131072

// gemm_sim v13 = v10 (validated 113us) + post-barrier issue reorder:
//   [vmcnt(4); barrier; issue b1 ds_reads; burst0 (prefetched bfn);
//    STAGE(g+3); burst1 (b1); RDNEXT(g+1)]
// Same slot/vmcnt protocol as v10 (stage->window map unchanged).
#define NGROUPS 32            // n-chunks (4096 cols each)
#define NT_PER  32            // 128-col n-tiles per block

typedef __attribute__((ext_vector_type(4))) float f32x4;
typedef __attribute__((ext_vector_type(8))) short bf16x8;
typedef __attribute__((ext_vector_type(4))) short bf16x4;

static __device__ inline unsigned short f2bf(float f) {
  unsigned u = __float_as_uint(f);
  unsigned r = u + 0x7FFFu + ((u >> 16) & 1u);  // round-to-nearest-even
  return (unsigned short)(r >> 16);
}

static __device__ inline bf16x8 cvt8(const float* __restrict__ p) {
  f32x4 a = *(const f32x4*)p;
  f32x4 b = *(const f32x4*)(p + 4);
  bf16x8 r;
  r[0] = (short)f2bf(a[0]); r[1] = (short)f2bf(a[1]);
  r[2] = (short)f2bf(a[2]); r[3] = (short)f2bf(a[3]);
  r[4] = (short)f2bf(b[0]); r[5] = (short)f2bf(b[1]);
  r[6] = (short)f2bf(b[2]); r[7] = (short)f2bf(b[3]);
  return r;
}

// K0: RT_bf[n][k] = bf16(R[k][n])   (256 x 2048)
__global__ void transpose_R(const float* __restrict__ R, unsigned short* __restrict__ rt) {
  int idx = blockIdx.x * 256 + threadIdx.x;
  int k = idx >> 8, n = idx & 255;
  rt[n * DIM + k] = f2bf(R[idx]);
}

// K1+K2 fused: blocks 0..31 = gemm_sketch; blocks 32..2079 = conv_buf.
__launch_bounds__(256)
__global__ void sketch_conv(const float* __restrict__ x, const unsigned short* __restrict__ rt,
                            unsigned short* __restrict__ sx,
                            const float* __restrict__ bufin, unsigned short* __restrict__ outb) {
  __shared__ unsigned short As[64][72];
  __shared__ unsigned short Bs[256][72];
  __shared__ float ssum[4][64];

  if (blockIdx.x >= 32) {
    // ---- conv path ----
    const int nvec = (NBUF * SKDIM) / 4;
    int stride = 2048 * 256;
    for (int i = (blockIdx.x - 32) * 256 + threadIdx.x; i < nvec; i += stride) {
      f32x4 v = ((const f32x4*)bufin)[i];
      bf16x4 r;
      r[0] = (short)f2bf(v[0]); r[1] = (short)f2bf(v[1]);
      r[2] = (short)f2bf(v[2]); r[3] = (short)f2bf(v[3]);
      ((bf16x4*)outb)[i] = r;
    }
    return;
  }

  // ---- sketch path (validated R0-R10) ----
  const int m0 = blockIdx.x * 64;
  const int tid = threadIdx.x;
  const int w = tid >> 6, l = tid & 63;
  const int lr = l & 15, q = l >> 4;

  f32x4 acc[4][4] = {};

  for (int k0 = 0; k0 < DIM; k0 += 64) {
    #pragma unroll
    for (int i = 0; i < 2; ++i) {
      int v = tid + i * 256;
      int r = v >> 3, vc = v & 7;
      *(bf16x8*)&As[r][vc * 8] = cvt8(x + (size_t)(m0 + r) * DIM + k0 + vc * 8);
    }
    #pragma unroll
    for (int i = 0; i < 8; ++i) {
      int v = tid + i * 256;
      int r = v >> 3, vc = v & 7;
      *(bf16x8*)&Bs[r][vc * 8] = *(const bf16x8*)(rt + (size_t)r * DIM + k0 + vc * 8);
    }
    __syncthreads();
    #pragma unroll
    for (int ks = 0; ks < 2; ++ks) {
      int kk = ks * 32 + q * 8;
      bf16x8 a[4], b[4];
      #pragma unroll
      for (int mi = 0; mi < 4; ++mi) a[mi] = *(bf16x8*)&As[mi * 16 + lr][kk];
      #pragma unroll
      for (int ni = 0; ni < 4; ++ni) b[ni] = *(bf16x8*)&Bs[w * 64 + ni * 16 + lr][kk];
      #pragma unroll
      for (int mi = 0; mi < 4; ++mi)
        #pragma unroll
        for (int ni = 0; ni < 4; ++ni)
          acc[mi][ni] = __builtin_amdgcn_mfma_f32_16x16x32_bf16(a[mi], b[ni], acc[mi][ni], 0, 0, 0);
    }
    __syncthreads();
  }

  float ps[4][4];
  #pragma unroll
  for (int mi = 0; mi < 4; ++mi)
    #pragma unroll
    for (int rg = 0; rg < 4; ++rg) {
      float s = acc[mi][0][rg] * acc[mi][0][rg] + acc[mi][1][rg] * acc[mi][1][rg]
              + acc[mi][2][rg] * acc[mi][2][rg] + acc[mi][3][rg] * acc[mi][3][rg];
      #pragma unroll
      for (int m = 1; m < 16; m <<= 1) s += __shfl_xor(s, m);
      ps[mi][rg] = s;
    }
  if (lr == 0) {
    #pragma unroll
    for (int mi = 0; mi < 4; ++mi)
      #pragma unroll
      for (int rg = 0; rg < 4; ++rg)
        ssum[w][mi * 16 + q * 4 + rg] = ps[mi][rg];
  }
  __syncthreads();

  #pragma unroll
  for (int mi = 0; mi < 4; ++mi)
    #pragma unroll
    for (int rg = 0; rg < 4; ++rg) {
      int r = mi * 16 + q * 4 + rg;
      float tot = ssum[0][r] + ssum[1][r] + ssum[2][r] + ssum[3][r];
      float inv = 1.0f / fmaxf(sqrtf(tot), 1e-12f);
      #pragma unroll
      for (int ni = 0; ni < 4; ++ni) {
        float val = acc[mi][ni][rg] * inv;
        sx[(size_t)(m0 + r) * SKDIM + w * 64 + ni * 16 + lr] = f2bf(val);
      }
    }
}

// K3 v13: A-in-regs, 16x16x32, 4 LDS slots, half cross-window prefetch (v10
// protocol, audited) with post-barrier reorder. Steady-state window g:
//   vmcnt(4) [slot g+1 confirmed]; s_barrier;
//   issue b1 <- slot g chunk1 (ds, fills under burst0);
//   burst0: 16 MFMA chunk0 (bfn, prefetched in window g-1);
//   STAGE(g+3);
//   burst1: 16 MFMA chunk1 (b1);
//   bfn <- slot g+1 chunk0 (prefetch for window g+1); fold at ks==3.
__launch_bounds__(256, 2)
__global__ void gemm_sim(const unsigned short* __restrict__ sx,
                         const unsigned short* __restrict__ bufb,
                         float* __restrict__ partial) {
  __shared__ __align__(16) char lb[65536];

  // XCD-chunked swizzle (512 blocks = 8 XCDs x 64), m-fastest inner.
  const int gid = blockIdx.x;
  const int logical = (gid & 7) * 64 + (gid >> 3);
  const int mt = logical & 15;       // 0..15 m-tile (128 rows)
  const int nc = logical >> 4;       // 0..31 n-chunk (4096 cols)
  const int m0 = mt * 128;
  const int ncbase = nc * (NT_PER * 128);

  const int tid = threadIdx.x;
  const int w = tid >> 6, l = tid & 63;
  const int wr = w >> 1, wc = w & 1;        // wave grid 2 x 2
  const int lr = l & 15, q = l >> 4;

  // staging: LDS linear dest (row = tid>>3 (+32j), 16B slot tid&7);
  // global source col-slot pre-swizzled by (row>>1)&7 = (tid>>4)&7.
  const int scol = ((tid & 7) ^ ((tid >> 4) & 7)) * 8;   // elements
  // read swizzle: chunk-c slot = (c*4+q) ^ ((lr>>1)&7)
  const int off0 = ((q ^ ((lr >> 1) & 7)) << 4);
  const int off1 = off0 ^ 64;
  const int rowoff = (wc * 64 + lr) * 128;

  // ---- A resident in registers: rows m0+wr*64+mi*16+lr, k = kc*32+q*8
  bf16x8 areg[4][8];
  {
    const unsigned short* abase = sx + (size_t)(m0 + wr * 64 + lr) * SKDIM + q * 8;
    #pragma unroll
    for (int mi = 0; mi < 4; ++mi)
      #pragma unroll
      for (int kc = 0; kc < 8; ++kc)
        areg[mi][kc] = *(const bf16x8*)(abase + mi * 16 * SKDIM + kc * 32);
  }

  f32x4 acc[4][4] = {};
  float rm[4][4];
  #pragma unroll
  for (int mi = 0; mi < 4; ++mi)
    #pragma unroll
    for (int rg = 0; rg < 4; ++rg) rm[mi][rg] = -3.0e38f;

  bf16x8 bfn[4];   // prefetched chunk-0 B frags for the upcoming window

#define STAGE(srcb, kpart, slot_) do {                                         \
    const unsigned short* s0_ = (srcb) + (kpart) * 64;                         \
    char* dst_ = lb + (slot_) * 16384 + tid * 16;                              \
    _Pragma("unroll")                                                          \
    for (int j_ = 0; j_ < 4; ++j_) {                                           \
      __builtin_amdgcn_global_load_lds(                                        \
          (const __attribute__((address_space(1))) unsigned int*)(s0_ + j_ * 32 * SKDIM), \
          (__attribute__((address_space(3))) unsigned int*)(dst_ + j_ * 4096), \
          16, 0, 0);                                                           \
    }                                                                          \
  } while (0)

#define RDNEXT(slotN)                                                          \
    _Pragma("unroll")                                                          \
    for (int ni = 0; ni < 4; ++ni)                                             \
      bfn[ni] = *(const bf16x8*)(lb + (slotN) * 16384 + rowoff + ni * 2048 + off0);

#define WINDOW(ks, VM, STAGE_STMT, RDNEXT_STMT) do {                           \
    asm volatile("s_waitcnt vmcnt(" #VM ")" ::: "memory");                     \
    asm volatile("s_barrier" ::: "memory");                                    \
    bf16x8 b1[4];                                                              \
    _Pragma("unroll")                                                          \
    for (int ni = 0; ni < 4; ++ni)                                             \
      b1[ni] = *(const bf16x8*)(lb + (ks) * 16384 + rowoff + ni * 2048 + off1); \
    __builtin_amdgcn_s_setprio(1);                                             \
    _Pragma("unroll")                                                          \
    for (int mi = 0; mi < 4; ++mi)                                             \
      _Pragma("unroll")                                                        \
      for (int ni = 0; ni < 4; ++ni)                                           \
        acc[mi][ni] = __builtin_amdgcn_mfma_f32_16x16x32_bf16(areg[mi][(ks) * 2], bfn[ni], acc[mi][ni], 0, 0, 0); \
    __builtin_amdgcn_s_setprio(0);                                             \
    STAGE_STMT;                                                                \
    __builtin_amdgcn_s_setprio(1);                                             \
    _Pragma("unroll")                                                          \
    for (int mi = 0; mi < 4; ++mi)                                             \
      _Pragma("unroll")                                                        \
      for (int ni = 0; ni < 4; ++ni)                                           \
        acc[mi][ni] = __builtin_amdgcn_mfma_f32_16x16x32_bf16(areg[mi][(ks) * 2 + 1], b1[ni], acc[mi][ni], 0, 0, 0); \
    __builtin_amdgcn_s_setprio(0);                                             \
    RDNEXT_STMT;                                                               \
  } while (0)

#define FOLD do {                                                              \
    _Pragma("unroll")                                                          \
    for (int mi = 0; mi < 4; ++mi)                                             \
      _Pragma("unroll")                                                        \
      for (int rg = 0; rg < 4; ++rg) {                                         \
        float v = fmaxf(fmaxf(acc[mi][0][rg], acc[mi][1][rg]),                 \
                        fmaxf(acc[mi][2][rg], acc[mi][3][rg]));                \
        rm[mi][rg] = fmaxf(rm[mi][rg], v);                                     \
        _Pragma("unroll")                                                      \
        for (int ni = 0; ni < 4; ++ni) acc[mi][ni][rg] = 0.0f;                 \
      }                                                                        \
  } while (0)

  const unsigned short* bsrc = bufb + (size_t)(ncbase + (tid >> 3)) * SKDIM + scol;

  // prologue: stage slots 0,1,2; confirm slot 0; prefetch its chunk0
  STAGE(bsrc, 0, 0);
  STAGE(bsrc, 1, 1);
  STAGE(bsrc, 2, 2);
  asm volatile("s_waitcnt vmcnt(8)" ::: "memory");
  asm volatile("s_barrier" ::: "memory");
  RDNEXT(0);

  for (int nt = 0; nt < NT_PER - 1; ++nt) {
    const unsigned short* bcur = bsrc;
    bsrc += 128 * SKDIM;
    WINDOW(0, 4, STAGE(bcur, 3, 3), RDNEXT(1));
    WINDOW(1, 4, STAGE(bsrc, 0, 0), RDNEXT(2));
    WINDOW(2, 4, STAGE(bsrc, 1, 1), RDNEXT(3));
    WINDOW(3, 4, STAGE(bsrc, 2, 2), RDNEXT(0));
    FOLD;
  }
  {  // tail n-tile (nt = NT_PER-1): no next-tile stages; drain counts
    const unsigned short* bcur = bsrc;
    WINDOW(0, 4, STAGE(bcur, 3, 3), RDNEXT(1));
    WINDOW(1, 4, (void)0, RDNEXT(2));
    WINDOW(2, 0, (void)0, RDNEXT(3));
    WINDOW(3, 0, (void)0, (void)0);
    FOLD;
  }
#undef STAGE
#undef RDNEXT
#undef WINDOW
#undef FOLD

  // epilogue: reduce over the 16 cols held across lr lanes
  #pragma unroll
  for (int mi = 0; mi < 4; ++mi)
    #pragma unroll
    for (int rg = 0; rg < 4; ++rg) {
      float v = rm[mi][rg];
      v = fmaxf(v, __shfl_xor(v, 1));
      v = fmaxf(v, __shfl_xor(v, 2));
      v = fmaxf(v, __shfl_xor(v, 4));
      v = fmaxf(v, __shfl_xor(v, 8));
      rm[mi][rg] = v;
    }

  float* rmaxs = (float*)lb;   // reuse staging LDS: [2 wc][128 rows]
  __syncthreads();
  if (lr == 0) {
    #pragma unroll
    for (int mi = 0; mi < 4; ++mi)
      #pragma unroll
      for (int rg = 0; rg < 4; ++rg)
        rmaxs[wc * 128 + wr * 64 + mi * 16 + q * 4 + rg] = rm[mi][rg];
  }
  __syncthreads();
  if (tid < 128) {
    float v = fmaxf(rmaxs[tid], rmaxs[128 + tid]);
    partial[(size_t)(m0 + tid) * NGROUPS + nc] = v;
  }
}

// K4: out[r] = 1 - max over 32 partials. 2 rows per 64-thread block.
__global__ void reduce_max(const float* __restrict__ partial, float* __restrict__ out) {
  const int r = blockIdx.x * 2 + (threadIdx.x >> 5);
  const int c = threadIdx.x & 31;
  float m = partial[(size_t)r * NGROUPS + c];
  #pragma unroll
  for (int s = 1; s < 32; s <<= 1) m = fmaxf(m, __shfl_xor(m, s));
  if (c == 0) out[r] = 1.0f - m;
}

extern "C" void kernel_launch(void* const* d_in, const int* in_sizes, int n_in,
                              void* d_out, int out_size, void* d_ws, size_t ws_size,
                              hipStream_t stream) {
  const float* x   = (const float*)d_in[0];   // [2048, 2048]
  const float* R   = (const float*)d_in[1];   // [2048, 256]
  const float* buf = (const float*)d_in[2];   // [131072, 256]
  float* out = (float*)d_out;                  // [2048]

  char* ws = (char*)d_ws;
  // ws layout: rt 1MB | buf_bf 64MB | sx_bf 1MB | partial 256KB
  unsigned short* rt   = (unsigned short*)(ws);
  unsigned short* bufb = (unsigned short*)(ws + (1ull << 20));
  unsigned short* sxb  = (unsigned short*)(ws + (1ull << 20) + (64ull << 20));
  float*          part = (float*)         (ws + (1ull << 20) + (64ull << 20) + (1ull << 20));

  transpose_R<<<dim3((DIM * SKDIM) / 256), dim3(256), 0, stream>>>(R, rt);
  sketch_conv<<<dim3(2080), dim3(256), 0, stream>>>(x, rt, sxb, buf, bufb);
  gemm_sim<<<dim3(512), dim3(256), 0, stream>>>(sxb, bufb, part);
  reduce_max<<<dim3(BROWS / 2), dim3(64), 0, stream>>>(part, out);
}

// Round 13
// 169.603 us; speedup vs baseline: 2.1582x; 1.0046x over previous
//
#include <hip/hip_runtime.h>
#include <hip/hip_bf16.h>

// Problem: B=2048, DIM=2048, SKETCH=256, SIZE=131072
//   sx = normalize_rows(x @ R); out = 1 - max_row(sx @ buffer^T)

#define BROWS 2048
#define DIM   2048
#define SKDIM 256
#define NBUF  131072

// gemm_sim v13 = v10 (validated 113us) + post-barrier issue reorder:
//   [vmcnt(4); barrier; issue b1 ds_reads; burst0 (prefetched bfn);
//    STAGE(g+3); burst1 (b1); RDNEXT(g+1)]
// Same slot/vmcnt protocol as v10 (stage->window map unchanged).
#define NGROUPS 32            // n-chunks (4096 cols each)
#define NT_PER  32            // 128-col n-tiles per block

typedef __attribute__((ext_vector_type(4))) float f32x4;
typedef __attribute__((ext_vector_type(8))) short bf16x8;
typedef __attribute__((ext_vector_type(4))) short bf16x4;

static __device__ inline unsigned short f2bf(float f) {
  unsigned u = __float_as_uint(f);
  unsigned r = u + 0x7FFFu + ((u >> 16) & 1u);  // round-to-nearest-even
  return (unsigned short)(r >> 16);
}

static __device__ inline bf16x8 cvt8(const float* __restrict__ p) {
  f32x4 a = *(const f32x4*)p;
  f32x4 b = *(const f32x4*)(p + 4);
  bf16x8 r;
  r[0] = (short)f2bf(a[0]); r[1] = (short)f2bf(a[1]);
  r[2] = (short)f2bf(a[2]); r[3] = (short)f2bf(a[3]);
  r[4] = (short)f2bf(b[0]); r[5] = (short)f2bf(b[1]);
  r[6] = (short)f2bf(b[2]); r[7] = (short)f2bf(b[3]);
  return r;
}

// K0: RT_bf[n][k] = bf16(R[k][n])   (256 x 2048)
__global__ void transpose_R(const float* __restrict__ R, unsigned short* __restrict__ rt) {
  int idx = blockIdx.x * 256 + threadIdx.x;
  int k = idx >> 8, n = idx & 255;
  rt[n * DIM + k] = f2bf(R[idx]);
}

// K1+K2 fused: blocks 0..31 = gemm_sketch; blocks 32..2079 = conv_buf.
__launch_bounds__(256)
__global__ void sketch_conv(const float* __restrict__ x, const unsigned short* __restrict__ rt,
                            unsigned short* __restrict__ sx,
                            const float* __restrict__ bufin, unsigned short* __restrict__ outb) {
  __shared__ unsigned short As[64][72];
  __shared__ unsigned short Bs[256][72];
  __shared__ float ssum[4][64];

  if (blockIdx.x >= 32) {
    // ---- conv path ----
    const int nvec = (NBUF * SKDIM) / 4;
    int stride = 2048 * 256;
    for (int i = (blockIdx.x - 32) * 256 + threadIdx.x; i < nvec; i += stride) {
      f32x4 v = ((const f32x4*)bufin)[i];
      bf16x4 r;
      r[0] = (short)f2bf(v[0]); r[1] = (short)f2bf(v[1]);
      r[2] = (short)f2bf(v[2]); r[3] = (short)f2bf(v[3]);
      ((bf16x4*)outb)[i] = r;
    }
    return;
  }

  // ---- sketch path (validated R0-R10) ----
  const int m0 = blockIdx.x * 64;
  const int tid = threadIdx.x;
  const int w = tid >> 6, l = tid & 63;
  const int lr = l & 15, q = l >> 4;

  f32x4 acc[4][4] = {};

  for (int k0 = 0; k0 < DIM; k0 += 64) {
    #pragma unroll
    for (int i = 0; i < 2; ++i) {
      int v = tid + i * 256;
      int r = v >> 3, vc = v & 7;
      *(bf16x8*)&As[r][vc * 8] = cvt8(x + (size_t)(m0 + r) * DIM + k0 + vc * 8);
    }
    #pragma unroll
    for (int i = 0; i < 8; ++i) {
      int v = tid + i * 256;
      int r = v >> 3, vc = v & 7;
      *(bf16x8*)&Bs[r][vc * 8] = *(const bf16x8*)(rt + (size_t)r * DIM + k0 + vc * 8);
    }
    __syncthreads();
    #pragma unroll
    for (int ks = 0; ks < 2; ++ks) {
      int kk = ks * 32 + q * 8;
      bf16x8 a[4], b[4];
      #pragma unroll
      for (int mi = 0; mi < 4; ++mi) a[mi] = *(bf16x8*)&As[mi * 16 + lr][kk];
      #pragma unroll
      for (int ni = 0; ni < 4; ++ni) b[ni] = *(bf16x8*)&Bs[w * 64 + ni * 16 + lr][kk];
      #pragma unroll
      for (int mi = 0; mi < 4; ++mi)
        #pragma unroll
        for (int ni = 0; ni < 4; ++ni)
          acc[mi][ni] = __builtin_amdgcn_mfma_f32_16x16x32_bf16(a[mi], b[ni], acc[mi][ni], 0, 0, 0);
    }
    __syncthreads();
  }

  float ps[4][4];
  #pragma unroll
  for (int mi = 0; mi < 4; ++mi)
    #pragma unroll
    for (int rg = 0; rg < 4; ++rg) {
      float s = acc[mi][0][rg] * acc[mi][0][rg] + acc[mi][1][rg] * acc[mi][1][rg]
              + acc[mi][2][rg] * acc[mi][2][rg] + acc[mi][3][rg] * acc[mi][3][rg];
      #pragma unroll
      for (int m = 1; m < 16; m <<= 1) s += __shfl_xor(s, m);
      ps[mi][rg] = s;
    }
  if (lr == 0) {
    #pragma unroll
    for (int mi = 0; mi < 4; ++mi)
      #pragma unroll
      for (int rg = 0; rg < 4; ++rg)
        ssum[w][mi * 16 + q * 4 + rg] = ps[mi][rg];
  }
  __syncthreads();

  #pragma unroll
  for (int mi = 0; mi < 4; ++mi)
    #pragma unroll
    for (int rg = 0; rg < 4; ++rg) {
      int r = mi * 16 + q * 4 + rg;
      float tot = ssum[0][r] + ssum[1][r] + ssum[2][r] + ssum[3][r];
      float inv = 1.0f / fmaxf(sqrtf(tot), 1e-12f);
      #pragma unroll
      for (int ni = 0; ni < 4; ++ni) {
        float val = acc[mi][ni][rg] * inv;
        sx[(size_t)(m0 + r) * SKDIM + w * 64 + ni * 16 + lr] = f2bf(val);
      }
    }
}

// K3 v13: A-in-regs, 16x16x32, 4 LDS slots, half cross-window prefetch (v10
// protocol, audited) with post-barrier reorder. Steady-state window g:
//   vmcnt(4) [slot g+1 confirmed]; s_barrier;
//   issue b1 <- slot g chunk1 (ds, fills under burst0);
//   burst0: 16 MFMA chunk0 (bfn, prefetched in window g-1);
//   STAGE(g+3);
//   burst1: 16 MFMA chunk1 (b1);
//   bfn <- slot g+1 chunk0 (prefetch for window g+1); fold at ks==3.
__launch_bounds__(256, 2)
__global__ void gemm_sim(const unsigned short* __restrict__ sx,
                         const unsigned short* __restrict__ bufb,
                         float* __restrict__ partial) {
  __shared__ __align__(16) char lb[65536];

  // XCD-chunked swizzle (512 blocks = 8 XCDs x 64), m-fastest inner.
  const int gid = blockIdx.x;
  const int logical = (gid & 7) * 64 + (gid >> 3);
  const int mt = logical & 15;       // 0..15 m-tile (128 rows)
  const int nc = logical >> 4;       // 0..31 n-chunk (4096 cols)
  const int m0 = mt * 128;
  const int ncbase = nc * (NT_PER * 128);

  const int tid = threadIdx.x;
  const int w = tid >> 6, l = tid & 63;
  const int wr = w >> 1, wc = w & 1;        // wave grid 2 x 2
  const int lr = l & 15, q = l >> 4;

  // staging: LDS linear dest (row = tid>>3 (+32j), 16B slot tid&7);
  // global source col-slot pre-swizzled by (row>>1)&7 = (tid>>4)&7.
  const int scol = ((tid & 7) ^ ((tid >> 4) & 7)) * 8;   // elements
  // read swizzle: chunk-c slot = (c*4+q) ^ ((lr>>1)&7)
  const int off0 = ((q ^ ((lr >> 1) & 7)) << 4);
  const int off1 = off0 ^ 64;
  const int rowoff = (wc * 64 + lr) * 128;

  // ---- A resident in registers: rows m0+wr*64+mi*16+lr, k = kc*32+q*8
  bf16x8 areg[4][8];
  {
    const unsigned short* abase = sx + (size_t)(m0 + wr * 64 + lr) * SKDIM + q * 8;
    #pragma unroll
    for (int mi = 0; mi < 4; ++mi)
      #pragma unroll
      for (int kc = 0; kc < 8; ++kc)
        areg[mi][kc] = *(const bf16x8*)(abase + mi * 16 * SKDIM + kc * 32);
  }

  f32x4 acc[4][4] = {};
  float rm[4][4];
  #pragma unroll
  for (int mi = 0; mi < 4; ++mi)
    #pragma unroll
    for (int rg = 0; rg < 4; ++rg) rm[mi][rg] = -3.0e38f;

  bf16x8 bfn[4];   // prefetched chunk-0 B frags for the upcoming window

#define STAGE(srcb, kpart, slot_) do {                                         \
    const unsigned short* s0_ = (srcb) + (kpart) * 64;                         \
    char* dst_ = lb + (slot_) * 16384 + tid * 16;                              \
    _Pragma("unroll")                                                          \
    for (int j_ = 0; j_ < 4; ++j_) {                                           \
      __builtin_amdgcn_global_load_lds(                                        \
          (const __attribute__((address_space(1))) unsigned int*)(s0_ + j_ * 32 * SKDIM), \
          (__attribute__((address_space(3))) unsigned int*)(dst_ + j_ * 4096), \
          16, 0, 0);                                                           \
    }                                                                          \
  } while (0)

#define RDNEXT(slotN)                                                          \
    _Pragma("unroll")                                                          \
    for (int ni = 0; ni < 4; ++ni)                                             \
      bfn[ni] = *(const bf16x8*)(lb + (slotN) * 16384 + rowoff + ni * 2048 + off0);

#define WINDOW(ks, VM, STAGE_STMT, RDNEXT_STMT) do {                           \
    asm volatile("s_waitcnt vmcnt(" #VM ")" ::: "memory");                     \
    asm volatile("s_barrier" ::: "memory");                                    \
    bf16x8 b1[4];                                                              \
    _Pragma("unroll")                                                          \
    for (int ni = 0; ni < 4; ++ni)                                             \
      b1[ni] = *(const bf16x8*)(lb + (ks) * 16384 + rowoff + ni * 2048 + off1); \
    __builtin_amdgcn_s_setprio(1);                                             \
    _Pragma("unroll")                                                          \
    for (int mi = 0; mi < 4; ++mi)                                             \
      _Pragma("unroll")                                                        \
      for (int ni = 0; ni < 4; ++ni)                                           \
        acc[mi][ni] = __builtin_amdgcn_mfma_f32_16x16x32_bf16(areg[mi][(ks) * 2], bfn[ni], acc[mi][ni], 0, 0, 0); \
    __builtin_amdgcn_s_setprio(0);                                             \
    STAGE_STMT;                                                                \
    __builtin_amdgcn_s_setprio(1);                                             \
    _Pragma("unroll")                                                          \
    for (int mi = 0; mi < 4; ++mi)                                             \
      _Pragma("unroll")                                                        \
      for (int ni = 0; ni < 4; ++ni)                                           \
        acc[mi][ni] = __builtin_amdgcn_mfma_f32_16x16x32_bf16(areg[mi][(ks) * 2 + 1], b1[ni], acc[mi][ni], 0, 0, 0); \
    __builtin_amdgcn_s_setprio(0);                                             \
    RDNEXT_STMT;                                                               \
  } while (0)

#define FOLD do {                                                              \
    _Pragma("unroll")                                                          \
    for (int mi = 0; mi < 4; ++mi)                                             \
      _Pragma("unroll")                                                        \
      for (int rg = 0; rg < 4; ++rg) {                                         \
        float v = fmaxf(fmaxf(acc[mi][0][rg], acc[mi][1][rg]),                 \
                        fmaxf(acc[mi][2][rg], acc[mi][3][rg]));                \
        rm[mi][rg] = fmaxf(rm[mi][rg], v);                                     \
        _Pragma("unroll")                                                      \
        for (int ni = 0; ni < 4; ++ni) acc[mi][ni][rg] = 0.0f;                 \
      }                                                                        \
  } while (0)

  const unsigned short* bsrc = bufb + (size_t)(ncbase + (tid >> 3)) * SKDIM + scol;

  // prologue: stage slots 0,1,2; confirm slot 0; prefetch its chunk0
  STAGE(bsrc, 0, 0);
  STAGE(bsrc, 1, 1);
  STAGE(bsrc, 2, 2);
  asm volatile("s_waitcnt vmcnt(8)" ::: "memory");
  asm volatile("s_barrier" ::: "memory");
  RDNEXT(0);

  for (int nt = 0; nt < NT_PER - 1; ++nt) {
    const unsigned short* bcur = bsrc;
    bsrc += 128 * SKDIM;
    WINDOW(0, 4, STAGE(bcur, 3, 3), RDNEXT(1));
    WINDOW(1, 4, STAGE(bsrc, 0, 0), RDNEXT(2));
    WINDOW(2, 4, STAGE(bsrc, 1, 1), RDNEXT(3));
    WINDOW(3, 4, STAGE(bsrc, 2, 2), RDNEXT(0));
    FOLD;
  }
  {  // tail n-tile (nt = NT_PER-1): no next-tile stages; drain counts
    const unsigned short* bcur = bsrc;
    WINDOW(0, 4, STAGE(bcur, 3, 3), RDNEXT(1));
    WINDOW(1, 4, (void)0, RDNEXT(2));
    WINDOW(2, 0, (void)0, RDNEXT(3));
    WINDOW(3, 0, (void)0, (void)0);
    FOLD;
  }
#undef STAGE
#undef RDNEXT
#undef WINDOW
#undef FOLD

  // epilogue: reduce over the 16 cols held across lr lanes
  #pragma unroll
  for (int mi = 0; mi < 4; ++mi)
    #pragma unroll
    for (int rg = 0; rg < 4; ++rg) {
      float v = rm[mi][rg];
      v = fmaxf(v, __shfl_xor(v, 1));
      v = fmaxf(v, __shfl_xor(v, 2));
      v = fmaxf(v, __shfl_xor(v, 4));
      v = fmaxf(v, __shfl_xor(v, 8));
      rm[mi][rg] = v;
    }

  float* rmaxs = (float*)lb;   // reuse staging LDS: [2 wc][128 rows]
  __syncthreads();
  if (lr == 0) {
    #pragma unroll
    for (int mi = 0; mi < 4; ++mi)
      #pragma unroll
      for (int rg = 0; rg < 4; ++rg)
        rmaxs[wc * 128 + wr * 64 + mi * 16 + q * 4 + rg] = rm[mi][rg];
  }
  __syncthreads();
  if (tid < 128) {
    float v = fmaxf(rmaxs[tid], rmaxs[128 + tid]);
    partial[(size_t)(m0 + tid) * NGROUPS + nc] = v;
  }
}

// K4: out[r] = 1 - max over 32 partials. 2 rows per 64-thread block.
__global__ void reduce_max(const float* __restrict__ partial, float* __restrict__ out) {
  const int r = blockIdx.x * 2 + (threadIdx.x >> 5);
  const int c = threadIdx.x & 31;
  float m = partial[(size_t)r * NGROUPS + c];
  #pragma unroll
  for (int s = 1; s < 32; s <<= 1) m = fmaxf(m, __shfl_xor(m, s));
  if (c == 0) out[r] = 1.0f - m;
}

extern "C" void kernel_launch(void* const* d_in, const int* in_sizes, int n_in,
                              void* d_out, int out_size, void* d_ws, size_t ws_size,
                              hipStream_t stream) {
  const float* x   = (const float*)d_in[0];   // [2048, 2048]
  const float* R   = (const float*)d_in[1];   // [2048, 256]
  const float* buf = (const float*)d_in[2];   // [131072, 256]
  float* out = (float*)d_out;                  // [2048]

  char* ws = (char*)d_ws;
  // ws layout: rt 1MB | buf_bf 64MB | sx_bf 1MB | partial 256KB
  unsigned short* rt   = (unsigned short*)(ws);
  unsigned short* bufb = (unsigned short*)(ws + (1ull << 20));
  unsigned short* sxb  = (unsigned short*)(ws + (1ull << 20) + (64ull << 20));
  float*          part = (float*)         (ws + (1ull << 20) + (64ull << 20) + (1ull << 20));

  transpose_R<<<dim3((DIM * SKDIM) / 256), dim3(256), 0, stream>>>(R, rt);
  sketch_conv<<<dim3(2080), dim3(256), 0, stream>>>(x, rt, sxb, buf, bufb);
  gemm_sim<<<dim3(512), dim3(256), 0, stream>>>(sxb, bufb, part);
  reduce_max<<<dim3(BROWS / 2), dim3(64), 0, stream>>>(part, out);
}

// Round 14
// 165.967 us; speedup vs baseline: 2.2055x; 1.0219x over previous
//
#include <hip/hip_runtime.h>
#include <hip/hip_bf16.h>

// Problem: B=2048, DIM=2048, SKETCH=256, SIZE=131072
//   sx = normalize_rows(x @ R); out = 1 - max_row(sx @ buffer^T)

#define BROWS 2048
#define DIM   2048
#define SKDIM 256
#define NBUF  131072

// gemm_sim v14: v10/v13 window body + WR=4. 512 threads (8 waves: wr in
// 0..3, wc in 0..1), block tile 256 rows x 128 cols per n-tile. Staged B
// panel now serves 4 row-groups -> LDS bytes/flop -17% vs v10 (96->80KB per
// equal work). Same 4-slot counted-vmcnt protocol (STAGE = 2 loads/thread
// at 512 thr, so head vmcnt = 2). 256 blocks (8 m x 32 nc), 1 block/CU.
#define NGROUPS 32            // n-chunks (4096 cols each)
#define NT_PER  32            // 128-col n-tiles per block

typedef __attribute__((ext_vector_type(4))) float f32x4;
typedef __attribute__((ext_vector_type(8))) short bf16x8;
typedef __attribute__((ext_vector_type(4))) short bf16x4;

static __device__ inline unsigned short f2bf(float f) {
  unsigned u = __float_as_uint(f);
  unsigned r = u + 0x7FFFu + ((u >> 16) & 1u);  // round-to-nearest-even
  return (unsigned short)(r >> 16);
}

static __device__ inline bf16x8 cvt8(const float* __restrict__ p) {
  f32x4 a = *(const f32x4*)p;
  f32x4 b = *(const f32x4*)(p + 4);
  bf16x8 r;
  r[0] = (short)f2bf(a[0]); r[1] = (short)f2bf(a[1]);
  r[2] = (short)f2bf(a[2]); r[3] = (short)f2bf(a[3]);
  r[4] = (short)f2bf(b[0]); r[5] = (short)f2bf(b[1]);
  r[6] = (short)f2bf(b[2]); r[7] = (short)f2bf(b[3]);
  return r;
}

// K0: RT_bf[n][k] = bf16(R[k][n])   (256 x 2048)
__global__ void transpose_R(const float* __restrict__ R, unsigned short* __restrict__ rt) {
  int idx = blockIdx.x * 256 + threadIdx.x;
  int k = idx >> 8, n = idx & 255;
  rt[n * DIM + k] = f2bf(R[idx]);
}

// K1+K2 fused: blocks 0..31 = gemm_sketch; blocks 32..2079 = conv_buf.
__launch_bounds__(256)
__global__ void sketch_conv(const float* __restrict__ x, const unsigned short* __restrict__ rt,
                            unsigned short* __restrict__ sx,
                            const float* __restrict__ bufin, unsigned short* __restrict__ outb) {
  __shared__ unsigned short As[64][72];
  __shared__ unsigned short Bs[256][72];
  __shared__ float ssum[4][64];

  if (blockIdx.x >= 32) {
    // ---- conv path ----
    const int nvec = (NBUF * SKDIM) / 4;
    int stride = 2048 * 256;
    for (int i = (blockIdx.x - 32) * 256 + threadIdx.x; i < nvec; i += stride) {
      f32x4 v = ((const f32x4*)bufin)[i];
      bf16x4 r;
      r[0] = (short)f2bf(v[0]); r[1] = (short)f2bf(v[1]);
      r[2] = (short)f2bf(v[2]); r[3] = (short)f2bf(v[3]);
      ((bf16x4*)outb)[i] = r;
    }
    return;
  }

  // ---- sketch path (validated R0-R12) ----
  const int m0 = blockIdx.x * 64;
  const int tid = threadIdx.x;
  const int w = tid >> 6, l = tid & 63;
  const int lr = l & 15, q = l >> 4;

  f32x4 acc[4][4] = {};

  for (int k0 = 0; k0 < DIM; k0 += 64) {
    #pragma unroll
    for (int i = 0; i < 2; ++i) {
      int v = tid + i * 256;
      int r = v >> 3, vc = v & 7;
      *(bf16x8*)&As[r][vc * 8] = cvt8(x + (size_t)(m0 + r) * DIM + k0 + vc * 8);
    }
    #pragma unroll
    for (int i = 0; i < 8; ++i) {
      int v = tid + i * 256;
      int r = v >> 3, vc = v & 7;
      *(bf16x8*)&Bs[r][vc * 8] = *(const bf16x8*)(rt + (size_t)r * DIM + k0 + vc * 8);
    }
    __syncthreads();
    #pragma unroll
    for (int ks = 0; ks < 2; ++ks) {
      int kk = ks * 32 + q * 8;
      bf16x8 a[4], b[4];
      #pragma unroll
      for (int mi = 0; mi < 4; ++mi) a[mi] = *(bf16x8*)&As[mi * 16 + lr][kk];
      #pragma unroll
      for (int ni = 0; ni < 4; ++ni) b[ni] = *(bf16x8*)&Bs[w * 64 + ni * 16 + lr][kk];
      #pragma unroll
      for (int mi = 0; mi < 4; ++mi)
        #pragma unroll
        for (int ni = 0; ni < 4; ++ni)
          acc[mi][ni] = __builtin_amdgcn_mfma_f32_16x16x32_bf16(a[mi], b[ni], acc[mi][ni], 0, 0, 0);
    }
    __syncthreads();
  }

  float ps[4][4];
  #pragma unroll
  for (int mi = 0; mi < 4; ++mi)
    #pragma unroll
    for (int rg = 0; rg < 4; ++rg) {
      float s = acc[mi][0][rg] * acc[mi][0][rg] + acc[mi][1][rg] * acc[mi][1][rg]
              + acc[mi][2][rg] * acc[mi][2][rg] + acc[mi][3][rg] * acc[mi][3][rg];
      #pragma unroll
      for (int m = 1; m < 16; m <<= 1) s += __shfl_xor(s, m);
      ps[mi][rg] = s;
    }
  if (lr == 0) {
    #pragma unroll
    for (int mi = 0; mi < 4; ++mi)
      #pragma unroll
      for (int rg = 0; rg < 4; ++rg)
        ssum[w][mi * 16 + q * 4 + rg] = ps[mi][rg];
  }
  __syncthreads();

  #pragma unroll
  for (int mi = 0; mi < 4; ++mi)
    #pragma unroll
    for (int rg = 0; rg < 4; ++rg) {
      int r = mi * 16 + q * 4 + rg;
      float tot = ssum[0][r] + ssum[1][r] + ssum[2][r] + ssum[3][r];
      float inv = 1.0f / fmaxf(sqrtf(tot), 1e-12f);
      #pragma unroll
      for (int ni = 0; ni < 4; ++ni) {
        float val = acc[mi][ni][rg] * inv;
        sx[(size_t)(m0 + r) * SKDIM + w * 64 + ni * 16 + lr] = f2bf(val);
      }
    }
}

// K3 v14: A-in-regs, 16x16x32, 4 LDS slots, v10 window protocol, WR=4.
// 8 waves: wr = w>>1 (4 row-groups of 64), wc = w&1 (2 col-groups of 64).
// Per wave: areg[4][8] (rows m0+wr*64+mi*16+lr), acc 4x4, same as v10.
// Steady-state window g (slot ks=g&3):
//   vmcnt(2) [slot g+1 confirmed: only STAGE(g+2)'s 2 loads outstanding];
//   s_barrier; issue b1 <- slot g chunk1; burst0 (bfn, prefetched);
//   STAGE(g+3) [2 gload_lds/thread]; burst1 (b1); bfn <- slot g+1 chunk0.
// LDS/window: stage 16KB + read 8 waves x 8KB = 80KB per 256x128x64 work
// (v10: 96KB per equal work).
__launch_bounds__(512, 2)
__global__ void gemm_sim(const unsigned short* __restrict__ sx,
                         const unsigned short* __restrict__ bufb,
                         float* __restrict__ partial) {
  __shared__ __align__(16) char lb[65536];

  // XCD-chunked swizzle (256 blocks = 8 XCDs x 32), m-fastest inner.
  const int gid = blockIdx.x;
  const int logical = (gid & 7) * 32 + (gid >> 3);
  const int mt = logical & 7;        // 0..7 m-tile (256 rows)
  const int nc = logical >> 3;       // 0..31 n-chunk (4096 cols)
  const int m0 = mt * 256;
  const int ncbase = nc * (NT_PER * 128);

  const int tid = threadIdx.x;
  const int w = tid >> 6, l = tid & 63;
  const int wr = w >> 1, wc = w & 1;        // wave grid 4 x 2
  const int lr = l & 15, q = l >> 4;

  // staging: 512 threads cover a 16KB slot in 2 8KB halves.
  // LDS linear dest: slot*16384 + tid*16 + j*8192  (row = tid>>3 + j*64).
  // global source col-slot pre-swizzled by (row>>1)&7 = (tid>>4)&7
  // (row+64 has the same key since 32 ≡ 0 mod 8).
  const int scol = ((tid & 7) ^ ((tid >> 4) & 7)) * 8;   // elements
  // read swizzle: chunk-c slot = (c*4+q) ^ ((lr>>1)&7)
  const int off0 = ((q ^ ((lr >> 1) & 7)) << 4);
  const int off1 = off0 ^ 64;
  const int rowoff = (wc * 64 + lr) * 128;

  // ---- A resident in registers: rows m0+wr*64+mi*16+lr, k = kc*32+q*8
  bf16x8 areg[4][8];
  {
    const unsigned short* abase = sx + (size_t)(m0 + wr * 64 + lr) * SKDIM + q * 8;
    #pragma unroll
    for (int mi = 0; mi < 4; ++mi)
      #pragma unroll
      for (int kc = 0; kc < 8; ++kc)
        areg[mi][kc] = *(const bf16x8*)(abase + mi * 16 * SKDIM + kc * 32);
  }

  f32x4 acc[4][4] = {};
  float rm[4][4];
  #pragma unroll
  for (int mi = 0; mi < 4; ++mi)
    #pragma unroll
    for (int rg = 0; rg < 4; ++rg) rm[mi][rg] = -3.0e38f;

  bf16x8 bfn[4];   // prefetched chunk-0 B frags for the upcoming window

#define STAGE(srcb, kpart, slot_) do {                                         \
    const unsigned short* s0_ = (srcb) + (kpart) * 64;                         \
    char* dst_ = lb + (slot_) * 16384 + tid * 16;                              \
    __builtin_amdgcn_global_load_lds(                                          \
        (const __attribute__((address_space(1))) unsigned int*)s0_,            \
        (__attribute__((address_space(3))) unsigned int*)dst_, 16, 0, 0);      \
    __builtin_amdgcn_global_load_lds(                                          \
        (const __attribute__((address_space(1))) unsigned int*)(s0_ + 64 * SKDIM), \
        (__attribute__((address_space(3))) unsigned int*)(dst_ + 8192), 16, 0, 0); \
  } while (0)

#define RDNEXT(slotN)                                                          \
    _Pragma("unroll")                                                          \
    for (int ni = 0; ni < 4; ++ni)                                             \
      bfn[ni] = *(const bf16x8*)(lb + (slotN) * 16384 + rowoff + ni * 2048 + off0);

#define WINDOW(ks, VM, STAGE_STMT, RDNEXT_STMT) do {                           \
    asm volatile("s_waitcnt vmcnt(" #VM ")" ::: "memory");                     \
    asm volatile("s_barrier" ::: "memory");                                    \
    bf16x8 b1[4];                                                              \
    _Pragma("unroll")                                                          \
    for (int ni = 0; ni < 4; ++ni)                                             \
      b1[ni] = *(const bf16x8*)(lb + (ks) * 16384 + rowoff + ni * 2048 + off1); \
    __builtin_amdgcn_s_setprio(1);                                             \
    _Pragma("unroll")                                                          \
    for (int mi = 0; mi < 4; ++mi)                                             \
      _Pragma("unroll")                                                        \
      for (int ni = 0; ni < 4; ++ni)                                           \
        acc[mi][ni] = __builtin_amdgcn_mfma_f32_16x16x32_bf16(areg[mi][(ks) * 2], bfn[ni], acc[mi][ni], 0, 0, 0); \
    __builtin_amdgcn_s_setprio(0);                                             \
    STAGE_STMT;                                                                \
    __builtin_amdgcn_s_setprio(1);                                             \
    _Pragma("unroll")                                                          \
    for (int mi = 0; mi < 4; ++mi)                                             \
      _Pragma("unroll")                                                        \
      for (int ni = 0; ni < 4; ++ni)                                           \
        acc[mi][ni] = __builtin_amdgcn_mfma_f32_16x16x32_bf16(areg[mi][(ks) * 2 + 1], b1[ni], acc[mi][ni], 0, 0, 0); \
    __builtin_amdgcn_s_setprio(0);                                             \
    RDNEXT_STMT;                                                               \
  } while (0)

#define FOLD do {                                                              \
    _Pragma("unroll")                                                          \
    for (int mi = 0; mi < 4; ++mi)                                             \
      _Pragma("unroll")                                                        \
      for (int rg = 0; rg < 4; ++rg) {                                         \
        float v = fmaxf(fmaxf(acc[mi][0][rg], acc[mi][1][rg]),                 \
                        fmaxf(acc[mi][2][rg], acc[mi][3][rg]));                \
        rm[mi][rg] = fmaxf(rm[mi][rg], v);                                     \
        _Pragma("unroll")                                                      \
        for (int ni = 0; ni < 4; ++ni) acc[mi][ni][rg] = 0.0f;                 \
      }                                                                        \
  } while (0)

  const unsigned short* bsrc = bufb + (size_t)(ncbase + (tid >> 3)) * SKDIM + scol;

  // prologue: stage slots 0,1,2 (6 loads); confirm slot 0 (leave 4); prefetch
  STAGE(bsrc, 0, 0);
  STAGE(bsrc, 1, 1);
  STAGE(bsrc, 2, 2);
  asm volatile("s_waitcnt vmcnt(4)" ::: "memory");
  asm volatile("s_barrier" ::: "memory");
  RDNEXT(0);

  for (int nt = 0; nt < NT_PER - 1; ++nt) {
    const unsigned short* bcur = bsrc;
    bsrc += 128 * SKDIM;
    WINDOW(0, 2, STAGE(bcur, 3, 3), RDNEXT(1));
    WINDOW(1, 2, STAGE(bsrc, 0, 0), RDNEXT(2));
    WINDOW(2, 2, STAGE(bsrc, 1, 1), RDNEXT(3));
    WINDOW(3, 2, STAGE(bsrc, 2, 2), RDNEXT(0));
    FOLD;
  }
  {  // tail n-tile (nt = NT_PER-1): no next-tile stages; drain counts
    const unsigned short* bcur = bsrc;
    WINDOW(0, 2, STAGE(bcur, 3, 3), RDNEXT(1));
    WINDOW(1, 2, (void)0, RDNEXT(2));
    WINDOW(2, 0, (void)0, RDNEXT(3));
    WINDOW(3, 0, (void)0, (void)0);
    FOLD;
  }
#undef STAGE
#undef RDNEXT
#undef WINDOW
#undef FOLD

  // epilogue: reduce over the 16 cols held across lr lanes
  #pragma unroll
  for (int mi = 0; mi < 4; ++mi)
    #pragma unroll
    for (int rg = 0; rg < 4; ++rg) {
      float v = rm[mi][rg];
      v = fmaxf(v, __shfl_xor(v, 1));
      v = fmaxf(v, __shfl_xor(v, 2));
      v = fmaxf(v, __shfl_xor(v, 4));
      v = fmaxf(v, __shfl_xor(v, 8));
      rm[mi][rg] = v;
    }

  float* rmaxs = (float*)lb;   // reuse staging LDS: [2 wc][256 rows]
  __syncthreads();
  if (lr == 0) {
    #pragma unroll
    for (int mi = 0; mi < 4; ++mi)
      #pragma unroll
      for (int rg = 0; rg < 4; ++rg)
        rmaxs[wc * 256 + wr * 64 + mi * 16 + q * 4 + rg] = rm[mi][rg];
  }
  __syncthreads();
  if (tid < 256) {
    float v = fmaxf(rmaxs[tid], rmaxs[256 + tid]);
    partial[(size_t)(m0 + tid) * NGROUPS + nc] = v;
  }
}

// K4: out[r] = 1 - max over 32 partials. 2 rows per 64-thread block.
__global__ void reduce_max(const float* __restrict__ partial, float* __restrict__ out) {
  const int r = blockIdx.x * 2 + (threadIdx.x >> 5);
  const int c = threadIdx.x & 31;
  float m = partial[(size_t)r * NGROUPS + c];
  #pragma unroll
  for (int s = 1; s < 32; s <<= 1) m = fmaxf(m, __shfl_xor(m, s));
  if (c == 0) out[r] = 1.0f - m;
}

extern "C" void kernel_launch(void* const* d_in, const int* in_sizes, int n_in,
                              void* d_out, int out_size, void* d_ws, size_t ws_size,
                              hipStream_t stream) {
  const float* x   = (const float*)d_in[0];   // [2048, 2048]
  const float* R   = (const float*)d_in[1];   // [2048, 256]
  const float* buf = (const float*)d_in[2];   // [131072, 256]
  float* out = (float*)d_out;                  // [2048]

  char* ws = (char*)d_ws;
  // ws layout: rt 1MB | buf_bf 64MB | sx_bf 1MB | partial 256KB
  unsigned short* rt   = (unsigned short*)(ws);
  unsigned short* bufb = (unsigned short*)(ws + (1ull << 20));
  unsigned short* sxb  = (unsigned short*)(ws + (1ull << 20) + (64ull << 20));
  float*          part = (float*)         (ws + (1ull << 20) + (64ull << 20) + (1ull << 20));

  transpose_R<<<dim3((DIM * SKDIM) / 256), dim3(256), 0, stream>>>(R, rt);
  sketch_conv<<<dim3(2080), dim3(256), 0, stream>>>(x, rt, sxb, buf, bufb);
  gemm_sim<<<dim3(256), dim3(512), 0, stream>>>(sxb, bufb, part);
  reduce_max<<<dim3(BROWS / 2), dim3(64), 0, stream>>>(part, out);
}